// Round 1
// baseline (900.399 us; speedup 1.0000x reference)
//
#include <hip/hip_runtime.h>
#include <stdint.h>

#define NGRAPH 2048
#define MNODES 128
#define HID 256
#define OUTC 12
#define NEDGE 2097152

typedef __attribute__((ext_vector_type(8))) short short8;
typedef __attribute__((ext_vector_type(4))) float v4f;

#define SLICE 64        // hidden columns per block
#define SWT_STRIDE 136  // node-dim stride (136 elem = 272 B, 16B-aligned, bank-friendly)

// packed f32x2 -> bf16x2, round-to-nearest-even (identical numerics to manual RNE)
__device__ __forceinline__ unsigned int cvtpk_bf16(float lo, float hi) {
    unsigned int r;
    asm("v_cvt_pk_bf16_f32 %0, %1, %2" : "=v"(r) : "v"(lo), "v"(hi));
    return r;
}

// ---- build: 4MB bitmask, fire-and-forget atomicOr (assignment semantics: all writers set 1)
__global__ void build_bits(const int* __restrict__ ei, unsigned int* __restrict__ bits) {
    int e = blockIdx.x * blockDim.x + threadIdx.x;
    if (e >= NEDGE) return;
    int sN = ei[e];
    int dN = ei[NEDGE + e];
    int g = sN >> 7;
    int li = sN & 127;
    int lj = dN & 127;
    unsigned int* base = bits + (size_t)g * (MNODES * 4);
    atomicOr(&base[li * 4 + (lj >> 5)], 1u << (lj & 31));
    atomicOr(&base[lj * 4 + (li >> 5)], 1u << (li & 31));
}

// ---- walk kernel: block = (graph, 64-col hidden slice). 4 waves; wave w owns
// rows (w>>1)*64..+63, cols (w&1)*32..+31 of the slice. A fragments live in
// registers for all 5 iterations; walk^T round-trips through 17KB of LDS.
// launch_bounds(256,5): 5 blocks/CU (20 waves) -- VGPR cap 102 >= observed 84, no spill.
__launch_bounds__(256, 5)
__global__ void walk2(const float* __restrict__ x,
                      const float* __restrict__ W,
                      const unsigned int* __restrict__ Abits,
                      float* __restrict__ partial) {
    __shared__ unsigned short sWT[SLICE][SWT_STRIDE];  // walk^T: [col][node]
    __shared__ float sVs2[2][6][SLICE];                // per-row-half col sums

    const int bx = blockIdx.x;
    const int g = bx >> 2;
    const int s = bx & 3;
    const int tid = threadIdx.x;
    const int wave = tid >> 6;
    const int lane = tid & 63;
    const int lrow = lane & 15;
    const int quad = lane >> 4;
    const int rhalf = wave >> 1;
    const int r0 = rhalf * 64;
    const int c0 = (wave & 1) * 32;      // col base within slice
    const int cg0 = s * SLICE + c0;      // global col base

    // ---- A fragments -> registers (fixed across iterations).
    // One coalesced uint4 per row (128 bits = full adjacency row), decode in regs.
    short8 areg[4][4];  // [rt][ks]
    {
        const uint4* Bg = (const uint4*)(Abits + (size_t)g * (MNODES * 4));
#pragma unroll
        for (int rt = 0; rt < 4; rt++) {
            uint4 w4 = Bg[r0 + rt * 16 + lrow];
#pragma unroll
            for (int ks = 0; ks < 4; ks++) {
                unsigned int w = (ks == 0 ? w4.x : ks == 1 ? w4.y : ks == 2 ? w4.z : w4.w) >> (quad * 8);
                short8 a;
#pragma unroll
                for (int j = 0; j < 8; j++)
                    a[j] = (short)(((w >> j) & 1u) ? 0x3F80 : 0);
                areg[rt][ks] = a;
            }
        }
    }

    // ---- X fragments (fp32, C-layout), init walk1 = X, v1 partial sums
    float xf[4][2][4];
    const float* xg = x + (size_t)g * (MNODES * HID);
#pragma unroll
    for (int rt = 0; rt < 4; rt++)
#pragma unroll
        for (int ct = 0; ct < 2; ct++) {
            int col = cg0 + ct * 16 + lrow;
#pragma unroll
            for (int reg = 0; reg < 4; reg++) {
                int row = r0 + rt * 16 + quad * 4 + reg;
                xf[rt][ct][reg] = xg[row * HID + col];
            }
        }
#pragma unroll
    for (int ct = 0; ct < 2; ct++) {
        int lcol = c0 + ct * 16 + lrow;
        float cs = 0.0f;
#pragma unroll
        for (int rt = 0; rt < 4; rt++) {
            int nbase = r0 + rt * 16 + quad * 4;
            uint2 u;
            u.x = cvtpk_bf16(xf[rt][ct][0], xf[rt][ct][1]);
            u.y = cvtpk_bf16(xf[rt][ct][2], xf[rt][ct][3]);
            *(uint2*)&sWT[lcol][nbase] = u;
            cs += xf[rt][ct][0] + xf[rt][ct][1] + xf[rt][ct][2] + xf[rt][ct][3];
        }
        cs += __shfl_xor(cs, 16);
        cs += __shfl_xor(cs, 32);
        if (quad == 0) sVs2[rhalf][0][lcol] = cs;   // waves of same rhalf own disjoint lcol
    }
    __syncthreads();

    // ---- 5 iterations: Y = A@walk (MFMA, A from regs), walk = Y.*X, col sums
    for (int it = 1; it <= 5; it++) {
        v4f acc[4][2];
#pragma unroll
        for (int rt = 0; rt < 4; rt++)
#pragma unroll
            for (int ct = 0; ct < 2; ct++) acc[rt][ct] = (v4f)(0.0f);
#pragma unroll
        for (int ks = 0; ks < 4; ks++) {
            int k0 = ks * 32 + quad * 8;
#pragma unroll
            for (int ct = 0; ct < 2; ct++) {
                short8 bf = *(const short8*)&sWT[c0 + ct * 16 + lrow][k0];
#pragma unroll
                for (int rt = 0; rt < 4; rt++)
                    acc[rt][ct] = __builtin_amdgcn_mfma_f32_16x16x32_bf16(areg[rt][ks], bf, acc[rt][ct], 0, 0, 0);
            }
        }
        __syncthreads();  // all reads done before overwrite
#pragma unroll
        for (int ct = 0; ct < 2; ct++) {
            int lcol = c0 + ct * 16 + lrow;
            float cs = 0.0f;
#pragma unroll
            for (int rt = 0; rt < 4; rt++) {
                float nw0 = acc[rt][ct][0] * xf[rt][ct][0];
                float nw1 = acc[rt][ct][1] * xf[rt][ct][1];
                float nw2 = acc[rt][ct][2] * xf[rt][ct][2];
                float nw3 = acc[rt][ct][3] * xf[rt][ct][3];
                int nbase = r0 + rt * 16 + quad * 4;
                uint2 u;
                u.x = cvtpk_bf16(nw0, nw1);
                u.y = cvtpk_bf16(nw2, nw3);
                *(uint2*)&sWT[lcol][nbase] = u;
                cs += nw0 + nw1 + nw2 + nw3;
            }
            cs += __shfl_xor(cs, 16);
            cs += __shfl_xor(cs, 32);
            if (quad == 0) sVs2[rhalf][it][lcol] = cs;
        }
        __syncthreads();  // walk ready for next iteration (also publishes sVs2)
    }

    // ---- per-block partial projection over this 6x64 slice of vs.
    // All 4 waves participate: 3 output channels each.
    {
        int cbase = wave * 3;
#pragma unroll
        for (int cc = 0; cc < 3; cc++) {
            int c = cbase + cc;
            const float* wr = W + c * (6 * HID) + s * SLICE;
            float p = 0.0f;
#pragma unroll
            for (int k = 0; k < 6; k++) {
                float v = sVs2[0][k][lane] + sVs2[1][k][lane];
                p += v * wr[k * HID + lane];
            }
#pragma unroll
            for (int off = 32; off >= 1; off >>= 1) p += __shfl_down(p, off);
            if (lane == 0) partial[bx * OUTC + c] = p;
        }
    }
}

// ---- combine the 4 slice partials + bias
__global__ void combine(const float* __restrict__ partial, const float* __restrict__ bvec,
                        float* __restrict__ out) {
    int i = blockIdx.x * blockDim.x + threadIdx.x;
    if (i >= NGRAPH * OUTC) return;
    int c = i % OUTC;
    int g = i / OUTC;
    float p = bvec[c];
#pragma unroll
    for (int s = 0; s < 4; s++) p += partial[(g * 4 + s) * OUTC + c];
    out[i] = p;
}

extern "C" void kernel_launch(void* const* d_in, const int* in_sizes, int n_in,
                              void* d_out, int out_size, void* d_ws, size_t ws_size,
                              hipStream_t stream) {
    const float* x = (const float*)d_in[0];
    const float* W = (const float*)d_in[1];
    const float* b = (const float*)d_in[2];
    const int* ei = (const int*)d_in[4];
    float* out = (float*)d_out;

    const size_t BITS = (size_t)NGRAPH * MNODES * 4 * sizeof(unsigned int);  // 4 MB

    unsigned int* bits = (unsigned int*)d_ws;
    float* partial = (float*)((char*)d_ws + BITS);
    hipMemsetAsync(bits, 0, BITS, stream);
    build_bits<<<NEDGE / 512, 512, 0, stream>>>(ei, bits);
    walk2<<<NGRAPH * 4, 256, 0, stream>>>(x, W, bits, partial);
    combine<<<(NGRAPH * OUTC + 255) / 256, 256, 0, stream>>>(partial, b, out);
}

// Round 2
// 668.293 us; speedup vs baseline: 1.3473x; 1.3473x over previous
//
#include <hip/hip_runtime.h>
#include <stdint.h>

#define NGRAPH 2048
#define MNODES 128
#define HID 256
#define OUTC 12
#define NEDGE 2097152

typedef __attribute__((ext_vector_type(8))) short short8;
typedef __attribute__((ext_vector_type(4))) float v4f;

#define SLICE 64        // hidden columns per block
#define SWT_STRIDE 136  // node-dim stride (136 elem = 272 B, 16B-aligned, bank-friendly)

// packed f32x2 -> bf16x2, round-to-nearest-even (identical numerics to manual RNE)
__device__ __forceinline__ unsigned int cvtpk_bf16(float lo, float hi) {
    unsigned int r;
    asm("v_cvt_pk_bf16_f32 %0, %1, %2" : "=v"(r) : "v"(lo), "v"(hi));
    return r;
}

// ---- build path A (fast): plain byte stores, no atomics.
// Assignment semantics: every writer writes 1, so races are benign & exact.
__global__ void build_bytes(const int* __restrict__ ei, unsigned char* __restrict__ Ab) {
    int e = blockIdx.x * blockDim.x + threadIdx.x;
    if (e >= NEDGE) return;
    int sN = ei[e];
    int dN = ei[NEDGE + e];
    int g = sN >> 7;
    int li = sN & 127;
    int lj = dN & 127;
    unsigned char* base = Ab + (size_t)g * (MNODES * MNODES);
    base[li * 128 + lj] = 1;
    base[lj * 128 + li] = 1;
}

// ---- build path B (fallback if ws too small): bitmask + atomicOr
__global__ void build_bits(const int* __restrict__ ei, unsigned int* __restrict__ bits) {
    int e = blockIdx.x * blockDim.x + threadIdx.x;
    if (e >= NEDGE) return;
    int sN = ei[e];
    int dN = ei[NEDGE + e];
    int g = sN >> 7;
    int li = sN & 127;
    int lj = dN & 127;
    unsigned int* base = bits + (size_t)g * (MNODES * 4);
    atomicOr(&base[li * 4 + (lj >> 5)], 1u << (lj & 31));
    atomicOr(&base[lj * 4 + (li >> 5)], 1u << (li & 31));
}

// ---- walk kernel: block = (graph, 64-col hidden slice). 4 waves; wave w owns
// rows (w>>1)*64..+63, cols (w&1)*32..+31 of the slice. A fragments live in
// registers for all 5 iterations; walk^T double-buffers through LDS.
// launch_bounds(256,4): cap 128 unified regs >= ~116 needed (84 arch + 32 acc)
// -- (256,5) capped at 102 and spilled 1.8 GB of scratch (round-1 post-mortem).
__launch_bounds__(256, 4)
__global__ void walk2(const float* __restrict__ x,
                      const float* __restrict__ W,
                      const unsigned char* __restrict__ Abytes,
                      const unsigned int* __restrict__ Abits,
                      int use_bytes,
                      float* __restrict__ partial) {
    __shared__ unsigned short sWT[2][SLICE][SWT_STRIDE];  // walk^T: [buf][col][node]
    __shared__ float sVs2[2][6][SLICE];                   // per-row-half col sums

    const int bx = blockIdx.x;
    const int g = bx >> 2;
    const int s = bx & 3;
    const int tid = threadIdx.x;
    const int wave = tid >> 6;
    const int lane = tid & 63;
    const int lrow = lane & 15;
    const int quad = lane >> 4;
    const int rhalf = wave >> 1;
    const int r0 = rhalf * 64;
    const int c0 = (wave & 1) * 32;      // col base within slice
    const int cg0 = s * SLICE + c0;      // global col base

    // ---- A fragments -> registers (fixed across iterations)
    short8 areg[4][4];  // [rt][ks]
    if (use_bytes) {
        const unsigned char* Ag = Abytes + (size_t)g * (MNODES * MNODES);
#pragma unroll
        for (int rt = 0; rt < 4; rt++) {
            int row = r0 + rt * 16 + lrow;
#pragma unroll
            for (int ks = 0; ks < 4; ks++) {
                int k0 = ks * 32 + quad * 8;
                uint2 u = *(const uint2*)(Ag + row * 128 + k0);
                short8 a;
#pragma unroll
                for (int j = 0; j < 8; j++) {
                    unsigned int byte = ((j < 4 ? u.x >> (8 * j) : u.y >> (8 * (j - 4))) & 0xFFu);
                    a[j] = (short)(byte ? 0x3F80 : 0);
                }
                areg[rt][ks] = a;
            }
        }
    } else {
        const unsigned int* Bg = Abits + (size_t)g * (MNODES * 4);
#pragma unroll
        for (int rt = 0; rt < 4; rt++) {
            int row = r0 + rt * 16 + lrow;
#pragma unroll
            for (int ks = 0; ks < 4; ks++) {
                unsigned int w = Bg[row * 4 + ks] >> (quad * 8);
                short8 a;
#pragma unroll
                for (int j = 0; j < 8; j++)
                    a[j] = (short)(((w >> j) & 1u) ? 0x3F80 : 0);
                areg[rt][ks] = a;
            }
        }
    }

    // ---- X fragments (fp32, C-layout), init walk1 = X (buf 0), v1 partial sums
    float xf[4][2][4];
    const float* xg = x + (size_t)g * (MNODES * HID);
#pragma unroll
    for (int rt = 0; rt < 4; rt++)
#pragma unroll
        for (int ct = 0; ct < 2; ct++) {
            int col = cg0 + ct * 16 + lrow;
#pragma unroll
            for (int reg = 0; reg < 4; reg++) {
                int row = r0 + rt * 16 + quad * 4 + reg;
                xf[rt][ct][reg] = xg[row * HID + col];
            }
        }
#pragma unroll
    for (int ct = 0; ct < 2; ct++) {
        int lcol = c0 + ct * 16 + lrow;
        float cs = 0.0f;
#pragma unroll
        for (int rt = 0; rt < 4; rt++) {
            int nbase = r0 + rt * 16 + quad * 4;
            uint2 u;
            u.x = cvtpk_bf16(xf[rt][ct][0], xf[rt][ct][1]);
            u.y = cvtpk_bf16(xf[rt][ct][2], xf[rt][ct][3]);
            *(uint2*)&sWT[0][lcol][nbase] = u;
            cs += xf[rt][ct][0] + xf[rt][ct][1] + xf[rt][ct][2] + xf[rt][ct][3];
        }
        cs += __shfl_xor(cs, 16);
        cs += __shfl_xor(cs, 32);
        if (quad == 0) sVs2[rhalf][0][lcol] = cs;   // waves of same rhalf own disjoint lcol
    }
    __syncthreads();

    // ---- 5 iterations: Y = A@walk (MFMA, A from regs), walk = Y.*X, col sums.
    // Double-buffered sWT: read buf cur, write buf nxt -> ONE barrier per iter.
    for (int it = 1; it <= 5; it++) {
        const int cur = (it - 1) & 1;
        const int nxt = it & 1;
        v4f acc[4][2];
#pragma unroll
        for (int rt = 0; rt < 4; rt++)
#pragma unroll
            for (int ct = 0; ct < 2; ct++) acc[rt][ct] = (v4f)(0.0f);
#pragma unroll
        for (int ks = 0; ks < 4; ks++) {
            int k0 = ks * 32 + quad * 8;
#pragma unroll
            for (int ct = 0; ct < 2; ct++) {
                short8 bf = *(const short8*)&sWT[cur][c0 + ct * 16 + lrow][k0];
#pragma unroll
                for (int rt = 0; rt < 4; rt++)
                    acc[rt][ct] = __builtin_amdgcn_mfma_f32_16x16x32_bf16(areg[rt][ks], bf, acc[rt][ct], 0, 0, 0);
            }
        }
#pragma unroll
        for (int ct = 0; ct < 2; ct++) {
            int lcol = c0 + ct * 16 + lrow;
            float cs = 0.0f;
#pragma unroll
            for (int rt = 0; rt < 4; rt++) {
                float nw0 = acc[rt][ct][0] * xf[rt][ct][0];
                float nw1 = acc[rt][ct][1] * xf[rt][ct][1];
                float nw2 = acc[rt][ct][2] * xf[rt][ct][2];
                float nw3 = acc[rt][ct][3] * xf[rt][ct][3];
                int nbase = r0 + rt * 16 + quad * 4;
                uint2 u;
                u.x = cvtpk_bf16(nw0, nw1);
                u.y = cvtpk_bf16(nw2, nw3);
                *(uint2*)&sWT[nxt][lcol][nbase] = u;
                cs += nw0 + nw1 + nw2 + nw3;
            }
            cs += __shfl_xor(cs, 16);
            cs += __shfl_xor(cs, 32);
            if (quad == 0) sVs2[rhalf][it][lcol] = cs;
        }
        __syncthreads();  // next-iter buffer ready (also publishes sVs2)
    }

    // ---- per-block partial projection over this 6x64 slice of vs.
    // All 4 waves participate: 3 output channels each.
    {
        int cbase = wave * 3;
#pragma unroll
        for (int cc = 0; cc < 3; cc++) {
            int c = cbase + cc;
            const float* wr = W + c * (6 * HID) + s * SLICE;
            float p = 0.0f;
#pragma unroll
            for (int k = 0; k < 6; k++) {
                float v = sVs2[0][k][lane] + sVs2[1][k][lane];
                p += v * wr[k * HID + lane];
            }
#pragma unroll
            for (int off = 32; off >= 1; off >>= 1) p += __shfl_down(p, off);
            if (lane == 0) partial[bx * OUTC + c] = p;
        }
    }
}

// ---- combine the 4 slice partials + bias
__global__ void combine(const float* __restrict__ partial, const float* __restrict__ bvec,
                        float* __restrict__ out) {
    int i = blockIdx.x * blockDim.x + threadIdx.x;
    if (i >= NGRAPH * OUTC) return;
    int c = i % OUTC;
    int g = i / OUTC;
    float p = bvec[c];
#pragma unroll
    for (int s = 0; s < 4; s++) p += partial[(g * 4 + s) * OUTC + c];
    out[i] = p;
}

extern "C" void kernel_launch(void* const* d_in, const int* in_sizes, int n_in,
                              void* d_out, int out_size, void* d_ws, size_t ws_size,
                              hipStream_t stream) {
    const float* x = (const float*)d_in[0];
    const float* W = (const float*)d_in[1];
    const float* b = (const float*)d_in[2];
    const int* ei = (const int*)d_in[4];
    float* out = (float*)d_out;

    const size_t ABYTES = (size_t)NGRAPH * MNODES * MNODES;        // 32 MB
    const size_t PARTIAL = (size_t)NGRAPH * 4 * OUTC * sizeof(float);

    if (ws_size >= ABYTES + PARTIAL) {
        unsigned char* Ab = (unsigned char*)d_ws;
        float* partial = (float*)((char*)d_ws + ABYTES);
        hipMemsetAsync(Ab, 0, ABYTES, stream);
        build_bytes<<<NEDGE / 256, 256, 0, stream>>>(ei, Ab);
        walk2<<<NGRAPH * 4, 256, 0, stream>>>(x, W, Ab, nullptr, 1, partial);
        combine<<<(NGRAPH * OUTC + 255) / 256, 256, 0, stream>>>(partial, b, out);
    } else {
        unsigned int* bits = (unsigned int*)d_ws;   // 4 MB
        float* partial = (float*)((char*)d_ws + (size_t)NGRAPH * MNODES * 4 * 4);
        hipMemsetAsync(bits, 0, (size_t)NGRAPH * MNODES * 4 * 4, stream);
        build_bits<<<NEDGE / 512, 512, 0, stream>>>(ei, bits);
        walk2<<<NGRAPH * 4, 256, 0, stream>>>(x, W, nullptr, bits, 0, partial);
        combine<<<(NGRAPH * OUTC + 255) / 256, 256, 0, stream>>>(partial, b, out);
    }
}

// Round 3
// 652.411 us; speedup vs baseline: 1.3801x; 1.0243x over previous
//
#include <hip/hip_runtime.h>
#include <stdint.h>

#define NGRAPH 2048
#define MNODES 128
#define HID 256
#define OUTC 12
#define NEDGE 2097152
#define CAP 1536   // bucket capacity per graph (mean 1024, sd 32 -> 16 sd margin)

typedef __attribute__((ext_vector_type(8))) short short8;
typedef __attribute__((ext_vector_type(4))) float v4f;

#define SLICE 64        // hidden columns per block
#define SWT_STRIDE 136  // node-dim stride (136 elem = 272 B, 16B-aligned, bank-friendly)

// packed f32x2 -> bf16x2, round-to-nearest-even (identical numerics to manual RNE)
__device__ __forceinline__ unsigned int cvtpk_bf16(float lo, float hi) {
    unsigned int r;
    asm("v_cvt_pk_bf16_f32 %0, %1, %2" : "=v"(r) : "v"(lo), "v"(hi));
    return r;
}

// ---- stage 1: bucket edges by graph. Cursor atomics hit 2048 L2-resident
// addresses; bucket writes are confined to per-graph 6KB regions (L2-friendly),
// unlike the old 4M random byte-stores thrashing a 32MB buffer across XCD L2s.
__global__ void scatter_edges(const int* __restrict__ ei,
                              unsigned int* __restrict__ buckets,
                              unsigned int* __restrict__ cursors) {
    int e = blockIdx.x * blockDim.x + threadIdx.x;
    if (e >= NEDGE) return;
    int sN = ei[e];
    int dN = ei[NEDGE + e];
    int g = sN >> 7;
    unsigned int slot = atomicAdd(&cursors[g], 1u);
    if (slot < CAP)
        buckets[(size_t)g * CAP + slot] = (unsigned)(sN & 127) | ((unsigned)(dN & 127) << 8);
}

// ---- stage 2: one block per graph; build 2KB adjacency bitmask in LDS
// (fast LDS atomics), write dense -> no global memset, no global RMW.
__global__ void build_from_buckets(const unsigned int* __restrict__ buckets,
                                   const unsigned int* __restrict__ cursors,
                                   unsigned int* __restrict__ bits) {
    __shared__ unsigned int sb[MNODES * 4];  // 128 rows x 128 bits
    int g = blockIdx.x;
    int t = threadIdx.x;
    for (int i = t; i < MNODES * 4; i += 256) sb[i] = 0;
    __syncthreads();
    unsigned int n = cursors[g];
    if (n > CAP) n = CAP;
    const unsigned int* bk = buckets + (size_t)g * CAP;
    for (unsigned int i = t; i < n; i += 256) {
        unsigned int p = bk[i];
        int li = p & 127;
        int lj = (p >> 8) & 127;
        atomicOr(&sb[li * 4 + (lj >> 5)], 1u << (lj & 31));
        atomicOr(&sb[lj * 4 + (li >> 5)], 1u << (li & 31));
    }
    __syncthreads();
    unsigned int* dst = bits + (size_t)g * (MNODES * 4);
    for (int i = t; i < MNODES * 4; i += 256) dst[i] = sb[i];
}

// ---- fallback (tiny ws): direct global atomicOr build (needs bits pre-zeroed)
__global__ void build_bits(const int* __restrict__ ei, unsigned int* __restrict__ bits) {
    int e = blockIdx.x * blockDim.x + threadIdx.x;
    if (e >= NEDGE) return;
    int sN = ei[e];
    int dN = ei[NEDGE + e];
    int g = sN >> 7;
    int li = sN & 127;
    int lj = dN & 127;
    unsigned int* base = bits + (size_t)g * (MNODES * 4);
    atomicOr(&base[li * 4 + (lj >> 5)], 1u << (lj & 31));
    atomicOr(&base[lj * 4 + (li >> 5)], 1u << (li & 31));
}

// ---- walk kernel: block = (graph, 64-col hidden slice). 4 waves; wave w owns
// rows (w>>1)*64..+63, cols (w&1)*32..+31 of the slice. A fragments live in
// registers for all 5 iterations; walk^T double-buffers through LDS (1 barrier/iter).
// launch_bounds(256,3): cap 170 regs; kernel needs ~150 (areg 64 + xf 32 + acc 32
// + temps). (256,4)=cap128 spilled 262MB scratch, (256,5)=cap102 spilled 1.8GB.
__launch_bounds__(256, 3)
__global__ void walk2(const float* __restrict__ x,
                      const float* __restrict__ W,
                      const unsigned int* __restrict__ Abits,
                      float* __restrict__ partial) {
    __shared__ unsigned short sWT[2][SLICE][SWT_STRIDE];  // walk^T: [buf][col][node]
    __shared__ float sVs2[2][6][SLICE];                   // per-row-half col sums

    const int bx = blockIdx.x;
    const int g = bx >> 2;
    const int s = bx & 3;
    const int tid = threadIdx.x;
    const int wave = tid >> 6;
    const int lane = tid & 63;
    const int lrow = lane & 15;
    const int quad = lane >> 4;
    const int rhalf = wave >> 1;
    const int r0 = rhalf * 64;
    const int c0 = (wave & 1) * 32;      // col base within slice
    const int cg0 = s * SLICE + c0;      // global col base

    // ---- A fragments -> registers (fixed across iterations).
    // One coalesced uint4 per row (128 bits = full adjacency row), decode in regs.
    short8 areg[4][4];  // [rt][ks]
    {
        const uint4* Bg = (const uint4*)(Abits + (size_t)g * (MNODES * 4));
#pragma unroll
        for (int rt = 0; rt < 4; rt++) {
            uint4 w4 = Bg[r0 + rt * 16 + lrow];
#pragma unroll
            for (int ks = 0; ks < 4; ks++) {
                unsigned int w = (ks == 0 ? w4.x : ks == 1 ? w4.y : ks == 2 ? w4.z : w4.w) >> (quad * 8);
                short8 a;
#pragma unroll
                for (int j = 0; j < 8; j++)
                    a[j] = (short)(((w >> j) & 1u) ? 0x3F80 : 0);
                areg[rt][ks] = a;
            }
        }
    }

    // ---- X fragments (fp32, C-layout), init walk1 = X (buf 0), v1 partial sums
    float xf[4][2][4];
    const float* xg = x + (size_t)g * (MNODES * HID);
#pragma unroll
    for (int rt = 0; rt < 4; rt++)
#pragma unroll
        for (int ct = 0; ct < 2; ct++) {
            int col = cg0 + ct * 16 + lrow;
#pragma unroll
            for (int reg = 0; reg < 4; reg++) {
                int row = r0 + rt * 16 + quad * 4 + reg;
                xf[rt][ct][reg] = xg[row * HID + col];
            }
        }
#pragma unroll
    for (int ct = 0; ct < 2; ct++) {
        int lcol = c0 + ct * 16 + lrow;
        float cs = 0.0f;
#pragma unroll
        for (int rt = 0; rt < 4; rt++) {
            int nbase = r0 + rt * 16 + quad * 4;
            uint2 u;
            u.x = cvtpk_bf16(xf[rt][ct][0], xf[rt][ct][1]);
            u.y = cvtpk_bf16(xf[rt][ct][2], xf[rt][ct][3]);
            *(uint2*)&sWT[0][lcol][nbase] = u;
            cs += xf[rt][ct][0] + xf[rt][ct][1] + xf[rt][ct][2] + xf[rt][ct][3];
        }
        cs += __shfl_xor(cs, 16);
        cs += __shfl_xor(cs, 32);
        if (quad == 0) sVs2[rhalf][0][lcol] = cs;   // waves of same rhalf own disjoint lcol
    }
    __syncthreads();

    // ---- 5 iterations: Y = A@walk (MFMA, A from regs), walk = Y.*X, col sums.
    // Double-buffered sWT: read buf cur, write buf nxt -> ONE barrier per iter.
    for (int it = 1; it <= 5; it++) {
        const int cur = (it - 1) & 1;
        const int nxt = it & 1;
        v4f acc[4][2];
#pragma unroll
        for (int rt = 0; rt < 4; rt++)
#pragma unroll
            for (int ct = 0; ct < 2; ct++) acc[rt][ct] = (v4f)(0.0f);
#pragma unroll
        for (int ks = 0; ks < 4; ks++) {
            int k0 = ks * 32 + quad * 8;
#pragma unroll
            for (int ct = 0; ct < 2; ct++) {
                short8 bf = *(const short8*)&sWT[cur][c0 + ct * 16 + lrow][k0];
#pragma unroll
                for (int rt = 0; rt < 4; rt++)
                    acc[rt][ct] = __builtin_amdgcn_mfma_f32_16x16x32_bf16(areg[rt][ks], bf, acc[rt][ct], 0, 0, 0);
            }
        }
#pragma unroll
        for (int ct = 0; ct < 2; ct++) {
            int lcol = c0 + ct * 16 + lrow;
            float cs = 0.0f;
#pragma unroll
            for (int rt = 0; rt < 4; rt++) {
                float nw0 = acc[rt][ct][0] * xf[rt][ct][0];
                float nw1 = acc[rt][ct][1] * xf[rt][ct][1];
                float nw2 = acc[rt][ct][2] * xf[rt][ct][2];
                float nw3 = acc[rt][ct][3] * xf[rt][ct][3];
                int nbase = r0 + rt * 16 + quad * 4;
                uint2 u;
                u.x = cvtpk_bf16(nw0, nw1);
                u.y = cvtpk_bf16(nw2, nw3);
                *(uint2*)&sWT[nxt][lcol][nbase] = u;
                cs += nw0 + nw1 + nw2 + nw3;
            }
            cs += __shfl_xor(cs, 16);
            cs += __shfl_xor(cs, 32);
            if (quad == 0) sVs2[rhalf][it][lcol] = cs;
        }
        __syncthreads();  // next-iter buffer ready (also publishes sVs2)
    }

    // ---- per-block partial projection over this 6x64 slice of vs.
    // All 4 waves participate: 3 output channels each.
    {
        int cbase = wave * 3;
#pragma unroll
        for (int cc = 0; cc < 3; cc++) {
            int c = cbase + cc;
            const float* wr = W + c * (6 * HID) + s * SLICE;
            float p = 0.0f;
#pragma unroll
            for (int k = 0; k < 6; k++) {
                float v = sVs2[0][k][lane] + sVs2[1][k][lane];
                p += v * wr[k * HID + lane];
            }
#pragma unroll
            for (int off = 32; off >= 1; off >>= 1) p += __shfl_down(p, off);
            if (lane == 0) partial[bx * OUTC + c] = p;
        }
    }
}

// ---- combine the 4 slice partials + bias
__global__ void combine(const float* __restrict__ partial, const float* __restrict__ bvec,
                        float* __restrict__ out) {
    int i = blockIdx.x * blockDim.x + threadIdx.x;
    if (i >= NGRAPH * OUTC) return;
    int c = i % OUTC;
    int g = i / OUTC;
    float p = bvec[c];
#pragma unroll
    for (int s = 0; s < 4; s++) p += partial[(g * 4 + s) * OUTC + c];
    out[i] = p;
}

extern "C" void kernel_launch(void* const* d_in, const int* in_sizes, int n_in,
                              void* d_out, int out_size, void* d_ws, size_t ws_size,
                              hipStream_t stream) {
    const float* x = (const float*)d_in[0];
    const float* W = (const float*)d_in[1];
    const float* b = (const float*)d_in[2];
    const int* ei = (const int*)d_in[4];
    float* out = (float*)d_out;

    const size_t BUCKETS = (size_t)NGRAPH * CAP * sizeof(unsigned int);        // 12 MB
    const size_t BITS    = (size_t)NGRAPH * MNODES * 4 * sizeof(unsigned int); // 4 MB
    const size_t CURS    = (size_t)NGRAPH * sizeof(unsigned int);              // 8 KB
    const size_t PARTIAL = (size_t)NGRAPH * 4 * OUTC * sizeof(float);          // 384 KB

    if (ws_size >= BUCKETS + BITS + CURS + PARTIAL) {
        unsigned int* buckets = (unsigned int*)d_ws;
        unsigned int* bits    = (unsigned int*)((char*)d_ws + BUCKETS);
        unsigned int* cursors = (unsigned int*)((char*)d_ws + BUCKETS + BITS);
        float* partial        = (float*)((char*)d_ws + BUCKETS + BITS + CURS);
        hipMemsetAsync(cursors, 0, CURS, stream);
        scatter_edges<<<NEDGE / 256, 256, 0, stream>>>(ei, buckets, cursors);
        build_from_buckets<<<NGRAPH, 256, 0, stream>>>(buckets, cursors, bits);
        walk2<<<NGRAPH * 4, 256, 0, stream>>>(x, W, bits, partial);
        combine<<<(NGRAPH * OUTC + 255) / 256, 256, 0, stream>>>(partial, b, out);
    } else {
        unsigned int* bits = (unsigned int*)d_ws;   // 4 MB
        float* partial = (float*)((char*)d_ws + BITS);
        hipMemsetAsync(bits, 0, BITS, stream);
        build_bits<<<NEDGE / 512, 512, 0, stream>>>(ei, bits);
        walk2<<<NGRAPH * 4, 256, 0, stream>>>(x, W, bits, partial);
        combine<<<(NGRAPH * OUTC + 255) / 256, 256, 0, stream>>>(partial, b, out);
    }
}

// Round 4
// 490.256 us; speedup vs baseline: 1.8366x; 1.3308x over previous
//
#include <hip/hip_runtime.h>
#include <stdint.h>

#define NGRAPH 2048
#define MNODES 128
#define HID 256
#define OUTC 12
#define NEDGE 2097152
#define NSUB 16     // sub-buckets per graph, keyed by blockIdx&15 (XCD-affine)
#define SUBCAP 160  // per-sub capacity (mean 64, sd ~8 -> 12 sd margin)
#define CURPAD 16   // cursor stride in uints (64B: one cache line per cursor)

typedef __attribute__((ext_vector_type(8))) short short8;
typedef __attribute__((ext_vector_type(4))) float v4f;

#define SLICE 64        // hidden columns per block
#define SWT_STRIDE 136  // node-dim stride (136 elem = 272 B, 16B-aligned, bank-friendly)

// packed f32x2 -> bf16x2, round-to-nearest-even (identical numerics to manual RNE)
__device__ __forceinline__ unsigned int cvtpk_bf16(float lo, float hi) {
    unsigned int r;
    asm("v_cvt_pk_bf16_f32 %0, %1, %2" : "=v"(r) : "v"(lo), "v"(hi));
    return r;
}

// ---- stage 1: bucket edges by (graph, blockIdx&15).
// Cursors padded to 64B (own line each -> 32K-way atomic parallelism, round-3
// fix: 16 cursors/line serialized at the coherence point = 255us).
// Sub-bucket writers all sit on one XCD (blockIdx round-robins XCDs) -> the
// 2MB per-XCD bucket slice stays in that XCD's private L2.
__global__ void scatter_edges(const int* __restrict__ ei,
                              unsigned int* __restrict__ buckets,
                              unsigned int* __restrict__ cursors) {
    int e = blockIdx.x * blockDim.x + threadIdx.x;
    if (e >= NEDGE) return;
    int sub = blockIdx.x & (NSUB - 1);
    int sN = ei[e];
    int dN = ei[NEDGE + e];
    int g = sN >> 7;
    unsigned int slot = atomicAdd(&cursors[(g * NSUB + sub) * CURPAD], 1u);
    if (slot < SUBCAP)
        buckets[((size_t)g * NSUB + sub) * SUBCAP + slot] =
            (unsigned)(sN & 127) | ((unsigned)(dN & 127) << 8);
}

// ---- stage 2: one block per graph; 16 threads per sub-bucket (all 256 busy),
// build 2KB adjacency bitmask in LDS (fast LDS atomics), write dense.
__global__ void build_from_buckets(const unsigned int* __restrict__ buckets,
                                   const unsigned int* __restrict__ cursors,
                                   unsigned int* __restrict__ bits) {
    __shared__ unsigned int sb[MNODES * 4];  // 128 rows x 128 bits
    int g = blockIdx.x;
    int t = threadIdx.x;
    for (int i = t; i < MNODES * 4; i += 256) sb[i] = 0;
    __syncthreads();
    int sub = t >> 4;   // 16 threads per sub-bucket
    int i0 = t & 15;
    unsigned int n = cursors[(g * NSUB + sub) * CURPAD];
    if (n > SUBCAP) n = SUBCAP;
    const unsigned int* bk = buckets + ((size_t)g * NSUB + sub) * SUBCAP;
    for (unsigned int i = i0; i < n; i += 16) {
        unsigned int p = bk[i];
        int li = p & 127;
        int lj = (p >> 8) & 127;
        atomicOr(&sb[li * 4 + (lj >> 5)], 1u << (lj & 31));
        atomicOr(&sb[lj * 4 + (li >> 5)], 1u << (li & 31));
    }
    __syncthreads();
    unsigned int* dst = bits + (size_t)g * (MNODES * 4);
    for (int i = t; i < MNODES * 4; i += 256) dst[i] = sb[i];
}

// ---- fallback (tiny ws): direct global atomicOr build (needs bits pre-zeroed)
__global__ void build_bits(const int* __restrict__ ei, unsigned int* __restrict__ bits) {
    int e = blockIdx.x * blockDim.x + threadIdx.x;
    if (e >= NEDGE) return;
    int sN = ei[e];
    int dN = ei[NEDGE + e];
    int g = sN >> 7;
    int li = sN & 127;
    int lj = dN & 127;
    unsigned int* base = bits + (size_t)g * (MNODES * 4);
    atomicOr(&base[li * 4 + (lj >> 5)], 1u << (lj & 31));
    atomicOr(&base[lj * 4 + (li >> 5)], 1u << (li & 31));
}

// ---- walk kernel: block = (graph, 64-col hidden slice). 4 waves; wave w owns
// rows (w>>1)*64..+63, cols (w&1)*32..+31 of the slice. A fragments live in
// registers for all 5 iterations; walk^T double-buffers through LDS (1 barrier/iter).
// launch_bounds(256,3): cap 170 regs; kernel needs ~150 (areg 64 + xf 32 + acc 32
// + temps). (256,4)=cap128 spilled 262MB scratch, (256,5)=cap102 spilled 1.8GB.
__launch_bounds__(256, 3)
__global__ void walk2(const float* __restrict__ x,
                      const float* __restrict__ W,
                      const unsigned int* __restrict__ Abits,
                      float* __restrict__ partial) {
    __shared__ unsigned short sWT[2][SLICE][SWT_STRIDE];  // walk^T: [buf][col][node]
    __shared__ float sVs2[2][6][SLICE];                   // per-row-half col sums

    const int bx = blockIdx.x;
    const int g = bx >> 2;
    const int s = bx & 3;
    const int tid = threadIdx.x;
    const int wave = tid >> 6;
    const int lane = tid & 63;
    const int lrow = lane & 15;
    const int quad = lane >> 4;
    const int rhalf = wave >> 1;
    const int r0 = rhalf * 64;
    const int c0 = (wave & 1) * 32;      // col base within slice
    const int cg0 = s * SLICE + c0;      // global col base

    // ---- A fragments -> registers (fixed across iterations).
    // One coalesced uint4 per row (128 bits = full adjacency row), decode in regs.
    short8 areg[4][4];  // [rt][ks]
    {
        const uint4* Bg = (const uint4*)(Abits + (size_t)g * (MNODES * 4));
#pragma unroll
        for (int rt = 0; rt < 4; rt++) {
            uint4 w4 = Bg[r0 + rt * 16 + lrow];
#pragma unroll
            for (int ks = 0; ks < 4; ks++) {
                unsigned int w = (ks == 0 ? w4.x : ks == 1 ? w4.y : ks == 2 ? w4.z : w4.w) >> (quad * 8);
                short8 a;
#pragma unroll
                for (int j = 0; j < 8; j++)
                    a[j] = (short)(((w >> j) & 1u) ? 0x3F80 : 0);
                areg[rt][ks] = a;
            }
        }
    }

    // ---- X fragments (fp32, C-layout), init walk1 = X (buf 0), v1 partial sums
    float xf[4][2][4];
    const float* xg = x + (size_t)g * (MNODES * HID);
#pragma unroll
    for (int rt = 0; rt < 4; rt++)
#pragma unroll
        for (int ct = 0; ct < 2; ct++) {
            int col = cg0 + ct * 16 + lrow;
#pragma unroll
            for (int reg = 0; reg < 4; reg++) {
                int row = r0 + rt * 16 + quad * 4 + reg;
                xf[rt][ct][reg] = xg[row * HID + col];
            }
        }
#pragma unroll
    for (int ct = 0; ct < 2; ct++) {
        int lcol = c0 + ct * 16 + lrow;
        float cs = 0.0f;
#pragma unroll
        for (int rt = 0; rt < 4; rt++) {
            int nbase = r0 + rt * 16 + quad * 4;
            uint2 u;
            u.x = cvtpk_bf16(xf[rt][ct][0], xf[rt][ct][1]);
            u.y = cvtpk_bf16(xf[rt][ct][2], xf[rt][ct][3]);
            *(uint2*)&sWT[0][lcol][nbase] = u;
            cs += xf[rt][ct][0] + xf[rt][ct][1] + xf[rt][ct][2] + xf[rt][ct][3];
        }
        cs += __shfl_xor(cs, 16);
        cs += __shfl_xor(cs, 32);
        if (quad == 0) sVs2[rhalf][0][lcol] = cs;   // waves of same rhalf own disjoint lcol
    }
    __syncthreads();

    // ---- 5 iterations: Y = A@walk (MFMA, A from regs), walk = Y.*X, col sums.
    // Double-buffered sWT: read buf cur, write buf nxt -> ONE barrier per iter.
    for (int it = 1; it <= 5; it++) {
        const int cur = (it - 1) & 1;
        const int nxt = it & 1;
        v4f acc[4][2];
#pragma unroll
        for (int rt = 0; rt < 4; rt++)
#pragma unroll
            for (int ct = 0; ct < 2; ct++) acc[rt][ct] = (v4f)(0.0f);
#pragma unroll
        for (int ks = 0; ks < 4; ks++) {
            int k0 = ks * 32 + quad * 8;
#pragma unroll
            for (int ct = 0; ct < 2; ct++) {
                short8 bf = *(const short8*)&sWT[cur][c0 + ct * 16 + lrow][k0];
#pragma unroll
                for (int rt = 0; rt < 4; rt++)
                    acc[rt][ct] = __builtin_amdgcn_mfma_f32_16x16x32_bf16(areg[rt][ks], bf, acc[rt][ct], 0, 0, 0);
            }
        }
#pragma unroll
        for (int ct = 0; ct < 2; ct++) {
            int lcol = c0 + ct * 16 + lrow;
            float cs = 0.0f;
#pragma unroll
            for (int rt = 0; rt < 4; rt++) {
                float nw0 = acc[rt][ct][0] * xf[rt][ct][0];
                float nw1 = acc[rt][ct][1] * xf[rt][ct][1];
                float nw2 = acc[rt][ct][2] * xf[rt][ct][2];
                float nw3 = acc[rt][ct][3] * xf[rt][ct][3];
                int nbase = r0 + rt * 16 + quad * 4;
                uint2 u;
                u.x = cvtpk_bf16(nw0, nw1);
                u.y = cvtpk_bf16(nw2, nw3);
                *(uint2*)&sWT[nxt][lcol][nbase] = u;
                cs += nw0 + nw1 + nw2 + nw3;
            }
            cs += __shfl_xor(cs, 16);
            cs += __shfl_xor(cs, 32);
            if (quad == 0) sVs2[rhalf][it][lcol] = cs;
        }
        __syncthreads();  // next-iter buffer ready (also publishes sVs2)
    }

    // ---- per-block partial projection over this 6x64 slice of vs.
    // All 4 waves participate: 3 output channels each.
    {
        int cbase = wave * 3;
#pragma unroll
        for (int cc = 0; cc < 3; cc++) {
            int c = cbase + cc;
            const float* wr = W + c * (6 * HID) + s * SLICE;
            float p = 0.0f;
#pragma unroll
            for (int k = 0; k < 6; k++) {
                float v = sVs2[0][k][lane] + sVs2[1][k][lane];
                p += v * wr[k * HID + lane];
            }
#pragma unroll
            for (int off = 32; off >= 1; off >>= 1) p += __shfl_down(p, off);
            if (lane == 0) partial[bx * OUTC + c] = p;
        }
    }
}

// ---- combine the 4 slice partials + bias
__global__ void combine(const float* __restrict__ partial, const float* __restrict__ bvec,
                        float* __restrict__ out) {
    int i = blockIdx.x * blockDim.x + threadIdx.x;
    if (i >= NGRAPH * OUTC) return;
    int c = i % OUTC;
    int g = i / OUTC;
    float p = bvec[c];
#pragma unroll
    for (int s = 0; s < 4; s++) p += partial[(g * 4 + s) * OUTC + c];
    out[i] = p;
}

extern "C" void kernel_launch(void* const* d_in, const int* in_sizes, int n_in,
                              void* d_out, int out_size, void* d_ws, size_t ws_size,
                              hipStream_t stream) {
    const float* x = (const float*)d_in[0];
    const float* W = (const float*)d_in[1];
    const float* b = (const float*)d_in[2];
    const int* ei = (const int*)d_in[4];
    float* out = (float*)d_out;

    const size_t BUCKETS = (size_t)NGRAPH * NSUB * SUBCAP * sizeof(unsigned int);   // 21 MB
    const size_t BITS    = (size_t)NGRAPH * MNODES * 4 * sizeof(unsigned int);      // 4 MB
    const size_t CURS    = (size_t)NGRAPH * NSUB * CURPAD * sizeof(unsigned int);   // 2 MB
    const size_t PARTIAL = (size_t)NGRAPH * 4 * OUTC * sizeof(float);               // 384 KB

    if (ws_size >= BUCKETS + BITS + CURS + PARTIAL) {
        unsigned int* buckets = (unsigned int*)d_ws;
        unsigned int* bits    = (unsigned int*)((char*)d_ws + BUCKETS);
        unsigned int* cursors = (unsigned int*)((char*)d_ws + BUCKETS + BITS);
        float* partial        = (float*)((char*)d_ws + BUCKETS + BITS + CURS);
        hipMemsetAsync(cursors, 0, CURS, stream);
        scatter_edges<<<NEDGE / 256, 256, 0, stream>>>(ei, buckets, cursors);
        build_from_buckets<<<NGRAPH, 256, 0, stream>>>(buckets, cursors, bits);
        walk2<<<NGRAPH * 4, 256, 0, stream>>>(x, W, bits, partial);
        combine<<<(NGRAPH * OUTC + 255) / 256, 256, 0, stream>>>(partial, b, out);
    } else {
        unsigned int* bits = (unsigned int*)d_ws;   // 4 MB
        float* partial = (float*)((char*)d_ws + BITS);
        hipMemsetAsync(bits, 0, BITS, stream);
        build_bits<<<NEDGE / 512, 512, 0, stream>>>(ei, bits);
        walk2<<<NGRAPH * 4, 256, 0, stream>>>(x, W, bits, partial);
        combine<<<(NGRAPH * OUTC + 255) / 256, 256, 0, stream>>>(partial, b, out);
    }
}